// Round 15
// baseline (194.409 us; speedup 1.0000x reference)
//
#include <hip/hip_runtime.h>
#include <hip/hip_bf16.h>

#define NQ      10
#define NLAYERS 4
#define D_IN    784
#define BLOCK   64             // ONE wave per workgroup; each wave simulates FOUR states.
#define NS      4
// LOCKED: occupancy floor stays 2 (min >=4 forces 64-VGPR compression + catastrophic
// scratch spill: R3/R5/R7, 760+ MB HBM writes). NEW (R15): max waves/EU = 2.
// RA model from R12/R14: under (2,8) the allocator chases the MAX-waves target —
// NS=2 -> 64 arch VGPR + AGPR round-trips (copies ate the ILP win), NS=4 -> 112 VGPR
// + 33 MB scratch spill. (2,2) gives a 256-reg budget and no compression incentive.
// Healthy kernel: WRITE_SIZE ~0.4 MB, FETCH ~13 MB. Watch for VGPR<=128 or WRITE>>1MB.
// LOCKED: reductions use plain __shfl_xor only (R8: DPP/Walsh/readlane reductions diverged
// nondeterministically across graph replays). DPP only in full-exec gate code (stable since R4).
// LOCKED: no permlane16/32_swap XOR-emulation (R13: +1.5k VALU inst on the busier pipe, -5%).
// R11 packed f2 math: 209->171. R12 2-state ILP: ->166. R13 permlane: 174 (reverted).
// R14 NS=4 under (2,8): 184 (partial spill; this round re-tests NS=4 under (2,2)).

// Amplitude index i (10 bits): i = lane(6 bits, i[9:4]) * 16 + r(4 bits, i[3:0]).
// Qubit q sits at bit P = 9-q.  P>=4 -> lane qubit (lane bit P-4), P<4 -> register qubit.

typedef __attribute__((ext_vector_type(2))) float f2;

__device__ __forceinline__ f2 cswapneg(f2 v) {   // i * v = (-im, re)
    f2 r; r.x = -v.y; r.y = v.x; return r;
}

template<int LB>
__device__ __forceinline__ float lane_xor(float v) {
    if constexpr (LB == 1) {        // quad_perm [1,0,3,2] — VALU (DPP)
        return __int_as_float(__builtin_amdgcn_update_dpp(
            0, __float_as_int(v), 0xB1, 0xF, 0xF, false));
    } else if constexpr (LB == 2) { // quad_perm [2,3,0,1] — VALU (DPP)
        return __int_as_float(__builtin_amdgcn_update_dpp(
            0, __float_as_int(v), 0x4E, 0xF, 0xF, false));
    } else {
        return __shfl_xor(v, LB, 64);   // masks 4..32 -> DS pipe
    }
}

template<int LB>
__device__ __forceinline__ f2 lane_xor2(f2 v) {
    f2 r; r.x = lane_xor<LB>(v.x); r.y = lane_xor<LB>(v.y); return r;
}

// ---- generic complex 2x2 gate (Rot) on bit position P, NS states interleaved ----
template<int P>
__device__ __forceinline__ void rot_gateN(f2 (&a)[NS][16], int lane, float4 gA, float4 gB) {
    if constexpr (P >= 4) {
        const int lb = 1 << (P - 4);
        const bool hi = (lane & lb) != 0;
        const float gdx = hi ? gB.z : gA.x, gdy = hi ? gB.w : gA.y;   // diagonal
        const float gox = hi ? gB.x : gA.z, goy = hi ? gB.y : gA.w;   // off-diagonal
#pragma unroll
        for (int r = 0; r < 16; r++) {
#pragma unroll
            for (int s = 0; s < NS; s++) {
                f2 o = lane_xor2<lb>(a[s][r]);
                f2 v = a[s][r];
                a[s][r] = gdx * v + gdy * cswapneg(v) + gox * o + goy * cswapneg(o);
            }
        }
    } else {
        const int m = 1 << P;
#pragma unroll
        for (int r = 0; r < 16; r++) {
            if (!(r & m)) {
                const int r1 = r | m;
#pragma unroll
                for (int s = 0; s < NS; s++) {
                    f2 A0 = a[s][r], A1 = a[s][r1];
                    f2 i0 = cswapneg(A0), i1 = cswapneg(A1);
                    a[s][r]  = gA.x * A0 + gA.y * i0 + gA.z * A1 + gA.w * i1;
                    a[s][r1] = gB.x * A0 + gB.y * i0 + gB.z * A1 + gB.w * i1;
                }
            }
        }
    }
}

// ---- layer-0 variant: per-state matrices (RY fused, angles differ per state) ----
template<int P>
__device__ __forceinline__ void rot_gateN_ab(f2 (&a)[NS][16], int lane,
                                             const float4 (&mA)[NS], const float4 (&mB)[NS]) {
    if constexpr (P >= 4) {
        const int lb = 1 << (P - 4);
        const bool hi = (lane & lb) != 0;
        float gdx[NS], gdy[NS], gox[NS], goy[NS];
#pragma unroll
        for (int s = 0; s < NS; s++) {
            gdx[s] = hi ? mB[s].z : mA[s].x;  gdy[s] = hi ? mB[s].w : mA[s].y;
            gox[s] = hi ? mB[s].x : mA[s].z;  goy[s] = hi ? mB[s].y : mA[s].w;
        }
#pragma unroll
        for (int r = 0; r < 16; r++) {
#pragma unroll
            for (int s = 0; s < NS; s++) {
                f2 o = lane_xor2<lb>(a[s][r]);
                f2 v = a[s][r];
                a[s][r] = gdx[s] * v + gdy[s] * cswapneg(v) + gox[s] * o + goy[s] * cswapneg(o);
            }
        }
    } else {
        const int m = 1 << P;
#pragma unroll
        for (int r = 0; r < 16; r++) {
            if (!(r & m)) {
                const int r1 = r | m;
#pragma unroll
                for (int s = 0; s < NS; s++) {
                    f2 A0 = a[s][r], A1 = a[s][r1];
                    f2 i0 = cswapneg(A0), i1 = cswapneg(A1);
                    a[s][r]  = mA[s].x * A0 + mA[s].y * i0 + mA[s].z * A1 + mA[s].w * i1;
                    a[s][r1] = mB[s].x * A0 + mB[s].y * i0 + mB[s].z * A1 + mB[s].w * i1;
                }
            }
        }
    }
}

// ---- rot<9> with the PREVIOUS layer's CNOT(ctrl=reg bit0, tgt=lane bit 32) fused in ----
__device__ __forceinline__ void rot9_fusedN(f2 (&a)[NS][16], int lane, float4 gA, float4 gB) {
    const bool hi = (lane & 32) != 0;
    const float gdx = hi ? gB.z : gA.x, gdy = hi ? gB.w : gA.y;
    const float gox = hi ? gB.x : gA.z, goy = hi ? gB.y : gA.w;
#pragma unroll
    for (int r = 0; r < 16; r++) {
#pragma unroll
        for (int s = 0; s < NS; s++) {
            f2 o = lane_xor2<32>(a[s][r]);
            f2 v = a[s][r];
            if (!(r & 1)) {
                a[s][r] = gdx * v + gdy * cswapneg(v) + gox * o + goy * cswapneg(o);
            } else {   // fused CNOT: own/partner roles swapped
                a[s][r] = gdx * o + gdy * cswapneg(o) + gox * v + goy * cswapneg(v);
            }
        }
    }
}

// ---- CNOT on all states: control bit PC, target bit PT ----
template<int PC, int PT>
__device__ __forceinline__ void cnot_gateN(f2 (&a)[NS][16], int lane) {
    if constexpr (PC >= 4 && PT < 4) {                // lane control, register target
        const int mt = 1 << PT;
        const bool ctl = (lane & (1 << (PC - 4))) != 0;
#pragma unroll
        for (int r = 0; r < 16; r++) {
            if (!(r & mt)) {
                const int r1 = r | mt;
#pragma unroll
                for (int s = 0; s < NS; s++) {
                    f2 A0 = a[s][r], A1 = a[s][r1];
                    f2 n0, n1;
                    n0.x = ctl ? A1.x : A0.x;  n0.y = ctl ? A1.y : A0.y;
                    n1.x = ctl ? A0.x : A1.x;  n1.y = ctl ? A0.y : A1.y;
                    a[s][r] = n0; a[s][r1] = n1;
                }
            }
        }
    } else if constexpr (PC < 4 && PT >= 4) {         // register control, lane target
        const int mc = 1 << PC, mt = 1 << (PT - 4);
#pragma unroll
        for (int r = 0; r < 16; r++) {
            if (r & mc) {
#pragma unroll
                for (int s = 0; s < NS; s++) {
                    a[s][r].x = __shfl_xor(a[s][r].x, mt, 64);
                    a[s][r].y = __shfl_xor(a[s][r].y, mt, 64);
                }
            }
        }
    } else {                                          // register-register: free rename
        const int mc = 1 << PC, mt = 1 << PT;
#pragma unroll
        for (int r = 0; r < 16; r++) {
            if ((r & mc) && !(r & mt)) {
                const int r1 = r | mt;
#pragma unroll
                for (int s = 0; s < NS; s++) {
                    f2 t = a[s][r]; a[s][r] = a[s][r1]; a[s][r1] = t;
                }
            }
        }
    }
}

__global__ __launch_bounds__(BLOCK)
__attribute__((amdgpu_waves_per_eu(2, 2)))
void qnet_kernel(
    const float* __restrict__ x,
    const float* __restrict__ Wp,
    const float* __restrict__ bp,
    const float* __restrict__ qw,
    const float* __restrict__ Wo,
    const float* __restrict__ bo,
    float* __restrict__ out, int B)
{
    __shared__ __align__(16) float gates[NLAYERS * NQ * 8];  // per-wave Rot matrix table

    const int lane = threadIdx.x;        // single wave per block
    const int s0   = blockIdx.x * NS;    // this wave's NS states

    // ---- Rot gate table (single wave: barrier is intra-wave, ~free) ----
    if (lane < NLAYERS * NQ) {
        float phi = qw[lane * 3 + 0];
        float th  = qw[lane * 3 + 1];
        float om  = qw[lane * 3 + 2];
        float s, c;   sincosf(0.5f * th, &s, &c);
        float sap, cap; sincosf(0.5f * (phi + om), &sap, &cap);
        float sam, cam; sincosf(0.5f * (phi - om), &sam, &cam);
        float* g = &gates[lane * 8];
        g[0] =  cap * c;  g[1] = -sap * c;   // u00
        g[2] = -cam * s;  g[3] = -sam * s;   // u01
        g[4] =  cam * s;  g[5] = -sam * s;   // u10
        g[6] =  cap * c;  g[7] =  sap * c;   // u11
    }
    __syncthreads();
    if (s0 >= B) return;

    // ---- projection for NS states (Wp value shared across states) ----
    float acc[NS][NQ];
#pragma unroll
    for (int s = 0; s < NS; s++)
#pragma unroll
        for (int q = 0; q < NQ; q++) acc[s][q] = 0.f;
    for (int d = lane; d < D_IN; d += 64) {
        float xv[NS];
#pragma unroll
        for (int s = 0; s < NS; s++) xv[s] = x[(size_t)(s0 + s) * D_IN + d];
#pragma unroll
        for (int q = 0; q < NQ; q++) {
            float w = Wp[q * D_IN + d];
#pragma unroll
            for (int s = 0; s < NS; s++) acc[s][q] += xv[s] * w;
        }
    }
#pragma unroll
    for (int s = 0; s < NS; s++)
#pragma unroll
        for (int q = 0; q < NQ; q++) {
#pragma unroll
            for (int o = 1; o < 64; o <<= 1) acc[s][q] += __shfl_xor(acc[s][q], o, 64);
        }
    float myc[NS], mys[NS];
#pragma unroll
    for (int s = 0; s < NS; s++) { myc[s] = 1.f; mys[s] = 0.f; }
    if (lane < NQ) {
#pragma unroll
        for (int s = 0; s < NS; s++) {
            float h = tanhf(acc[s][lane] + bp[lane]);
            sincosf(0.5f * h, &mys[s], &myc[s]);
        }
    }

    // ---- statevectors |0..0> in registers, packed (re,im) ----
    f2 a[NS][16];
#pragma unroll
    for (int s = 0; s < NS; s++)
#pragma unroll
        for (int r = 0; r < 16; r++) { a[s][r].x = 0.f; a[s][r].y = 0.f; }
    if (lane == 0) {
#pragma unroll
        for (int s = 0; s < NS; s++) a[s][0].x = 1.f;
    }

    // Pull-index for the composite lane-CNOT chain: src_lane = Gray(lane)
    const int bidx = (lane ^ (lane >> 1)) << 2;

    // ---- layer 0: RY fused into Rot (per-state matrices) ----
    {
        const float* gl = &gates[0];
#define FROTQ(Q) \
        { float4 gA = *(const float4*)(gl + Q * 8); \
          float4 gB = *(const float4*)(gl + Q * 8 + 4); \
          float4 mA[NS], mB[NS]; \
          _Pragma("unroll") \
          for (int s = 0; s < NS; s++) { \
            float c = __shfl(myc[s], Q, 64), ss = __shfl(mys[s], Q, 64); \
            mA[s].x = gA.x * c + gA.z * ss;  mA[s].y = gA.y * c + gA.w * ss; \
            mA[s].z = gA.z * c - gA.x * ss;  mA[s].w = gA.w * c - gA.y * ss; \
            mB[s].x = gB.x * c + gB.z * ss;  mB[s].y = gB.y * c + gB.w * ss; \
            mB[s].z = gB.z * c - gB.x * ss;  mB[s].w = gB.w * c - gB.y * ss; \
          } \
          rot_gateN_ab<9 - Q>(a, lane, mA, mB); }
        FROTQ(0) FROTQ(1) FROTQ(2) FROTQ(3) FROTQ(4)
        FROTQ(5) FROTQ(6) FROTQ(7) FROTQ(8) FROTQ(9)
#undef FROTQ
        // CNOT ring (9,8)..(5,4) as one lane permutation, all states
#pragma unroll
        for (int r = 0; r < 16; r++) {
#pragma unroll
            for (int s = 0; s < NS; s++) {
                a[s][r].x = __int_as_float(__builtin_amdgcn_ds_bpermute(bidx, __float_as_int(a[s][r].x)));
                a[s][r].y = __int_as_float(__builtin_amdgcn_ds_bpermute(bidx, __float_as_int(a[s][r].y)));
            }
        }
        cnot_gateN<4, 3>(a, lane);
        cnot_gateN<3, 2>(a, lane);
        cnot_gateN<2, 1>(a, lane);
        cnot_gateN<1, 0>(a, lane);
        // cnot<0,9> fused into next layer's rot<9>
    }

    // ---- layers 1..3 (first gate consumes previous layer's trailing cnot<0,9>) ----
    for (int l = 1; l < NLAYERS; l++) {
        const float* gl = &gates[l * NQ * 8];
        {   float4 gA = *(const float4*)(gl);
            float4 gB = *(const float4*)(gl + 4);
            rot9_fusedN(a, lane, gA, gB); }
#define ROTQ(Q) { float4 gA = *(const float4*)(gl + Q * 8); \
                  float4 gB = *(const float4*)(gl + Q * 8 + 4); \
                  rot_gateN<9 - Q>(a, lane, gA, gB); }
        ROTQ(1) ROTQ(2) ROTQ(3) ROTQ(4)
        ROTQ(5) ROTQ(6) ROTQ(7) ROTQ(8) ROTQ(9)
#undef ROTQ
#pragma unroll
        for (int r = 0; r < 16; r++) {
#pragma unroll
            for (int s = 0; s < NS; s++) {
                a[s][r].x = __int_as_float(__builtin_amdgcn_ds_bpermute(bidx, __float_as_int(a[s][r].x)));
                a[s][r].y = __int_as_float(__builtin_amdgcn_ds_bpermute(bidx, __float_as_int(a[s][r].y)));
            }
        }
        cnot_gateN<4, 3>(a, lane);
        cnot_gateN<3, 2>(a, lane);
        cnot_gateN<2, 1>(a, lane);
        cnot_gateN<1, 0>(a, lane);
    }
    // layer 3's trailing cnot<0,9> applied for real (measurement follows)
    cnot_gateN<0, 9>(a, lane);

    // ---- measurement: Z expectation per qubit, all states ----
    float zq[NS][NQ];
#pragma unroll
    for (int s = 0; s < NS; s++) {
        float S = 0.f, z3 = 0.f, z2 = 0.f, z1 = 0.f, z0 = 0.f;
#pragma unroll
        for (int r = 0; r < 16; r++) {
            float p = a[s][r].x * a[s][r].x + a[s][r].y * a[s][r].y;
            S += p;
            z3 += (r & 8) ? -p : p;
            z2 += (r & 4) ? -p : p;
            z1 += (r & 2) ? -p : p;
            z0 += (r & 1) ? -p : p;
        }
        zq[s][6] = z3; zq[s][7] = z2; zq[s][8] = z1; zq[s][9] = z0;   // register qubits
#pragma unroll
        for (int q = 0; q < 6; q++)                                    // lane qubits: bit 5-q
            zq[s][q] = ((lane >> (5 - q)) & 1) ? -S : S;
    }
#pragma unroll
    for (int s = 0; s < NS; s++)
#pragma unroll
        for (int q = 0; q < NQ; q++) {
#pragma unroll
            for (int o = 1; o < 64; o <<= 1) zq[s][q] += __shfl_xor(zq[s][q], o, 64);
        }

    // ---- output projection: out = zq @ Wo^T + bo, all states ----
    if (lane < NQ) {
        const float* wrow = Wo + lane * NQ;
        float bb = bo[lane];
#pragma unroll
        for (int s = 0; s < NS; s++) {
            float o = bb;
#pragma unroll
            for (int q = 0; q < NQ; q++) o += zq[s][q] * wrow[q];
            out[(size_t)(s0 + s) * NQ + lane] = o;
        }
    }
}

extern "C" void kernel_launch(void* const* d_in, const int* in_sizes, int n_in,
                              void* d_out, int out_size, void* d_ws, size_t ws_size,
                              hipStream_t stream) {
    const float* x  = (const float*)d_in[0];
    const float* Wp = (const float*)d_in[1];
    const float* bp = (const float*)d_in[2];
    const float* qw = (const float*)d_in[3];
    const float* Wo = (const float*)d_in[4];
    const float* bo = (const float*)d_in[5];
    float* out = (float*)d_out;

    const int B = in_sizes[0] / D_IN;                    // 8192 states, NS per wave/block
    const int blocks = (B + NS - 1) / NS;
    hipLaunchKernelGGL(qnet_kernel, dim3(blocks), dim3(BLOCK), 0, stream,
                       x, Wp, bp, qw, Wo, bo, out, B);
}

// Round 16
// 167.173 us; speedup vs baseline: 1.1629x; 1.1629x over previous
//
#include <hip/hip_runtime.h>
#include <hip/hip_bf16.h>

#define NQ      10
#define NLAYERS 4
#define D_IN    784
#define BLOCK   64             // ONE wave per workgroup; each wave simulates TWO states.
// RA model (R12/R14/R15): backend never allocates >~112 arch VGPRs for this kernel —
// it compresses via AGPR copies (NS=2 @ (2,8): 64 VGPR), scratch spill (NS=4 @ (2,8):
// 33 MB writes), or LDS spill (NS=4 @ (2,2): LDS 1536->11776, 10x bank conflicts).
// NS=4 is therefore dead. R16: NS=2 with waves_per_eu(2,4) — 128-reg max-occupancy
// target exactly fits NS=2 without AGPR round-trips.
// LOCKED: occupancy floor (min) stays 2: min>=4 forces 64-VGPR + catastrophic scratch
// spill (R3/R5/R7, 760+ MB HBM writes). Healthy: WRITE ~0.4 MB, FETCH ~13 MB, LDS 1536.
// LOCKED: reductions use plain __shfl_xor only (R8: DPP/Walsh/readlane diverged across
// graph replays). DPP only in full-exec gate code (stable since R4).
// LOCKED: no permlane16/32_swap XOR-emulation (R13: +VALU on the busier pipe, -5%).
// R11 packed f2: 209->171. R12 2-state: ->166 (best). R13: 174. R14: 184. R15: 194.

// Amplitude index i (10 bits): i = lane(6 bits, i[9:4]) * 16 + r(4 bits, i[3:0]).
// Qubit q sits at bit P = 9-q.  P>=4 -> lane qubit (lane bit P-4), P<4 -> register qubit.

typedef __attribute__((ext_vector_type(2))) float f2;

__device__ __forceinline__ f2 cswapneg(f2 v) {   // i * v = (-im, re)
    f2 r; r.x = -v.y; r.y = v.x; return r;
}

template<int LB>
__device__ __forceinline__ float lane_xor(float v) {
    if constexpr (LB == 1) {        // quad_perm [1,0,3,2] — VALU (DPP)
        return __int_as_float(__builtin_amdgcn_update_dpp(
            0, __float_as_int(v), 0xB1, 0xF, 0xF, false));
    } else if constexpr (LB == 2) { // quad_perm [2,3,0,1] — VALU (DPP)
        return __int_as_float(__builtin_amdgcn_update_dpp(
            0, __float_as_int(v), 0x4E, 0xF, 0xF, false));
    } else {
        return __shfl_xor(v, LB, 64);   // masks 4..32 -> DS pipe
    }
}

template<int LB>
__device__ __forceinline__ f2 lane_xor2(f2 v) {
    f2 r; r.x = lane_xor<LB>(v.x); r.y = lane_xor<LB>(v.y); return r;
}

// ---- generic complex 2x2 gate (Rot) on bit position P, two states interleaved ----
template<int P>
__device__ __forceinline__ void rot_gate2(f2 (&a)[16], f2 (&b)[16], int lane,
                                          float4 gA, float4 gB) {
    if constexpr (P >= 4) {
        const int lb = 1 << (P - 4);
        const bool hi = (lane & lb) != 0;
        const float gdx = hi ? gB.z : gA.x, gdy = hi ? gB.w : gA.y;   // diagonal
        const float gox = hi ? gB.x : gA.z, goy = hi ? gB.y : gA.w;   // off-diagonal
#pragma unroll
        for (int r = 0; r < 16; r++) {
            f2 oa = lane_xor2<lb>(a[r]);
            f2 ob = lane_xor2<lb>(b[r]);
            f2 va = a[r], vb = b[r];
            a[r] = gdx * va + gdy * cswapneg(va) + gox * oa + goy * cswapneg(oa);
            b[r] = gdx * vb + gdy * cswapneg(vb) + gox * ob + goy * cswapneg(ob);
        }
    } else {
        const int m = 1 << P;
#pragma unroll
        for (int r = 0; r < 16; r++) {
            if (!(r & m)) {
                const int r1 = r | m;
                f2 A0 = a[r], A1 = a[r1];
                f2 B0 = b[r], B1 = b[r1];
                f2 ia0 = cswapneg(A0), ia1 = cswapneg(A1);
                f2 ib0 = cswapneg(B0), ib1 = cswapneg(B1);
                a[r]  = gA.x * A0 + gA.y * ia0 + gA.z * A1 + gA.w * ia1;
                b[r]  = gA.x * B0 + gA.y * ib0 + gA.z * B1 + gA.w * ib1;
                a[r1] = gB.x * A0 + gB.y * ia0 + gB.z * A1 + gB.w * ia1;
                b[r1] = gB.x * B0 + gB.y * ib0 + gB.z * B1 + gB.w * ib1;
            }
        }
    }
}

// ---- layer-0 variant: per-state matrices (RY fused, angles differ per state) ----
template<int P>
__device__ __forceinline__ void rot_gate2ab(f2 (&a)[16], f2 (&b)[16], int lane,
                                            float4 aAm, float4 aBm,
                                            float4 bAm, float4 bBm) {
    if constexpr (P >= 4) {
        const int lb = 1 << (P - 4);
        const bool hi = (lane & lb) != 0;
        const float adx = hi ? aBm.z : aAm.x, ady = hi ? aBm.w : aAm.y;
        const float aox = hi ? aBm.x : aAm.z, aoy = hi ? aBm.y : aAm.w;
        const float bdx = hi ? bBm.z : bAm.x, bdy = hi ? bBm.w : bAm.y;
        const float box = hi ? bBm.x : bAm.z, boy = hi ? bBm.y : bAm.w;
#pragma unroll
        for (int r = 0; r < 16; r++) {
            f2 oa = lane_xor2<lb>(a[r]);
            f2 ob = lane_xor2<lb>(b[r]);
            f2 va = a[r], vb = b[r];
            a[r] = adx * va + ady * cswapneg(va) + aox * oa + aoy * cswapneg(oa);
            b[r] = bdx * vb + bdy * cswapneg(vb) + box * ob + boy * cswapneg(ob);
        }
    } else {
        const int m = 1 << P;
#pragma unroll
        for (int r = 0; r < 16; r++) {
            if (!(r & m)) {
                const int r1 = r | m;
                f2 A0 = a[r], A1 = a[r1];
                f2 B0 = b[r], B1 = b[r1];
                f2 ia0 = cswapneg(A0), ia1 = cswapneg(A1);
                f2 ib0 = cswapneg(B0), ib1 = cswapneg(B1);
                a[r]  = aAm.x * A0 + aAm.y * ia0 + aAm.z * A1 + aAm.w * ia1;
                b[r]  = bAm.x * B0 + bAm.y * ib0 + bAm.z * B1 + bAm.w * ib1;
                a[r1] = aBm.x * A0 + aBm.y * ia0 + aBm.z * A1 + aBm.w * ia1;
                b[r1] = bBm.x * B0 + bBm.y * ib0 + bBm.z * B1 + bBm.w * ib1;
            }
        }
    }
}

// ---- rot<9> with the PREVIOUS layer's CNOT(ctrl=reg bit0, tgt=lane bit 32) fused in ----
__device__ __forceinline__ void rot9_fused2(f2 (&a)[16], f2 (&b)[16], int lane,
                                            float4 gA, float4 gB) {
    const bool hi = (lane & 32) != 0;
    const float gdx = hi ? gB.z : gA.x, gdy = hi ? gB.w : gA.y;
    const float gox = hi ? gB.x : gA.z, goy = hi ? gB.y : gA.w;
#pragma unroll
    for (int r = 0; r < 16; r++) {
        f2 oa; oa.x = __shfl_xor(a[r].x, 32, 64); oa.y = __shfl_xor(a[r].y, 32, 64);
        f2 ob; ob.x = __shfl_xor(b[r].x, 32, 64); ob.y = __shfl_xor(b[r].y, 32, 64);
        f2 va = a[r], vb = b[r];
        if (!(r & 1)) {
            a[r] = gdx * va + gdy * cswapneg(va) + gox * oa + goy * cswapneg(oa);
            b[r] = gdx * vb + gdy * cswapneg(vb) + gox * ob + goy * cswapneg(ob);
        } else {   // fused CNOT: own/partner roles swapped
            a[r] = gdx * oa + gdy * cswapneg(oa) + gox * va + goy * cswapneg(va);
            b[r] = gdx * ob + gdy * cswapneg(ob) + gox * vb + goy * cswapneg(vb);
        }
    }
}

// ---- CNOT on both states: control bit PC, target bit PT ----
template<int PC, int PT>
__device__ __forceinline__ void cnot_gate2(f2 (&a)[16], f2 (&b)[16], int lane) {
    if constexpr (PC >= 4 && PT < 4) {                // lane control, register target
        const int mt = 1 << PT;
        const bool ctl = (lane & (1 << (PC - 4))) != 0;
#pragma unroll
        for (int r = 0; r < 16; r++) {
            if (!(r & mt)) {
                const int r1 = r | mt;
                f2 A0 = a[r], A1 = a[r1], B0 = b[r], B1 = b[r1];
                f2 na0, na1, nb0, nb1;
                na0.x = ctl ? A1.x : A0.x;  na0.y = ctl ? A1.y : A0.y;
                na1.x = ctl ? A0.x : A1.x;  na1.y = ctl ? A0.y : A1.y;
                nb0.x = ctl ? B1.x : B0.x;  nb0.y = ctl ? B1.y : B0.y;
                nb1.x = ctl ? B0.x : B1.x;  nb1.y = ctl ? B0.y : B1.y;
                a[r] = na0; a[r1] = na1; b[r] = nb0; b[r1] = nb1;
            }
        }
    } else if constexpr (PC < 4 && PT >= 4) {         // register control, lane target
        const int mc = 1 << PC, mt = 1 << (PT - 4);
#pragma unroll
        for (int r = 0; r < 16; r++) {
            if (r & mc) {
                a[r].x = __shfl_xor(a[r].x, mt, 64);
                a[r].y = __shfl_xor(a[r].y, mt, 64);
                b[r].x = __shfl_xor(b[r].x, mt, 64);
                b[r].y = __shfl_xor(b[r].y, mt, 64);
            }
        }
    } else {                                          // register-register: free rename
        const int mc = 1 << PC, mt = 1 << PT;
#pragma unroll
        for (int r = 0; r < 16; r++) {
            if ((r & mc) && !(r & mt)) {
                const int r1 = r | mt;
                f2 t = a[r]; a[r] = a[r1]; a[r1] = t;
                f2 u = b[r]; b[r] = b[r1]; b[r1] = u;
            }
        }
    }
}

__global__ __launch_bounds__(BLOCK)
__attribute__((amdgpu_waves_per_eu(2, 4)))
void qnet_kernel(
    const float* __restrict__ x,
    const float* __restrict__ Wp,
    const float* __restrict__ bp,
    const float* __restrict__ qw,
    const float* __restrict__ Wo,
    const float* __restrict__ bo,
    float* __restrict__ out, int B)
{
    __shared__ __align__(16) float gates[NLAYERS * NQ * 8];  // per-wave Rot matrix table

    const int lane = threadIdx.x;       // single wave per block
    const int s0   = blockIdx.x * 2;    // this wave's two states
    const int s1   = s0 + 1;

    // ---- Rot gate table (single wave: barrier is intra-wave, ~free) ----
    if (lane < NLAYERS * NQ) {
        float phi = qw[lane * 3 + 0];
        float th  = qw[lane * 3 + 1];
        float om  = qw[lane * 3 + 2];
        float s, c;   sincosf(0.5f * th, &s, &c);
        float sap, cap; sincosf(0.5f * (phi + om), &sap, &cap);
        float sam, cam; sincosf(0.5f * (phi - om), &sam, &cam);
        float* g = &gates[lane * 8];
        g[0] =  cap * c;  g[1] = -sap * c;   // u00
        g[2] = -cam * s;  g[3] = -sam * s;   // u01
        g[4] =  cam * s;  g[5] = -sam * s;   // u10
        g[6] =  cap * c;  g[7] =  sap * c;   // u11
    }
    __syncthreads();
    if (s0 >= B) return;

    // ---- projection for both states (Wp value shared) ----
    float acc0[NQ], acc1[NQ];
#pragma unroll
    for (int q = 0; q < NQ; q++) { acc0[q] = 0.f; acc1[q] = 0.f; }
    const float* xr0 = x + (size_t)s0 * D_IN;
    const float* xr1 = x + (size_t)s1 * D_IN;
    for (int d = lane; d < D_IN; d += 64) {
        float x0 = xr0[d], x1 = xr1[d];
#pragma unroll
        for (int q = 0; q < NQ; q++) {
            float w = Wp[q * D_IN + d];
            acc0[q] += x0 * w;
            acc1[q] += x1 * w;
        }
    }
#pragma unroll
    for (int q = 0; q < NQ; q++) {
#pragma unroll
        for (int o = 1; o < 64; o <<= 1) {
            acc0[q] += __shfl_xor(acc0[q], o, 64);
            acc1[q] += __shfl_xor(acc1[q], o, 64);
        }
    }
    float myc0 = 1.f, mys0 = 0.f, myc1 = 1.f, mys1 = 0.f;
    if (lane < NQ) {
        float h0 = tanhf(acc0[lane] + bp[lane]);
        float h1 = tanhf(acc1[lane] + bp[lane]);
        sincosf(0.5f * h0, &mys0, &myc0);
        sincosf(0.5f * h1, &mys1, &myc1);
    }

    // ---- statevectors |0..0> in registers, packed (re,im) ----
    f2 a[16], b[16];
#pragma unroll
    for (int r = 0; r < 16; r++) { a[r].x = 0.f; a[r].y = 0.f; b[r].x = 0.f; b[r].y = 0.f; }
    if (lane == 0) { a[0].x = 1.f; b[0].x = 1.f; }

    // Pull-index for the composite lane-CNOT chain: src_lane = Gray(lane)
    const int bidx = (lane ^ (lane >> 1)) << 2;

    // ---- layer 0: RY fused into Rot (per-state matrices) ----
    {
        const float* gl = &gates[0];
        float c0, ss0, c1, ss1;
#define FROTQ(Q) \
        c0 = __shfl(myc0, Q, 64); ss0 = __shfl(mys0, Q, 64); \
        c1 = __shfl(myc1, Q, 64); ss1 = __shfl(mys1, Q, 64); \
        { float4 gA = *(const float4*)(gl + Q * 8); \
          float4 gB = *(const float4*)(gl + Q * 8 + 4); \
          float4 aAm, aBm, bAm, bBm; \
          aAm.x = gA.x * c0 + gA.z * ss0;  aAm.y = gA.y * c0 + gA.w * ss0; \
          aAm.z = gA.z * c0 - gA.x * ss0;  aAm.w = gA.w * c0 - gA.y * ss0; \
          aBm.x = gB.x * c0 + gB.z * ss0;  aBm.y = gB.y * c0 + gB.w * ss0; \
          aBm.z = gB.z * c0 - gB.x * ss0;  aBm.w = gB.w * c0 - gB.y * ss0; \
          bAm.x = gA.x * c1 + gA.z * ss1;  bAm.y = gA.y * c1 + gA.w * ss1; \
          bAm.z = gA.z * c1 - gA.x * ss1;  bAm.w = gA.w * c1 - gA.y * ss1; \
          bBm.x = gB.x * c1 + gB.z * ss1;  bBm.y = gB.y * c1 + gB.w * ss1; \
          bBm.z = gB.z * c1 - gB.x * ss1;  bBm.w = gB.w * c1 - gB.y * ss1; \
          rot_gate2ab<9 - Q>(a, b, lane, aAm, aBm, bAm, bBm); }
        FROTQ(0) FROTQ(1) FROTQ(2) FROTQ(3) FROTQ(4)
        FROTQ(5) FROTQ(6) FROTQ(7) FROTQ(8) FROTQ(9)
#undef FROTQ
        // CNOT ring (9,8)..(5,4) as one lane permutation, both states
#pragma unroll
        for (int r = 0; r < 16; r++) {
            a[r].x = __int_as_float(__builtin_amdgcn_ds_bpermute(bidx, __float_as_int(a[r].x)));
            a[r].y = __int_as_float(__builtin_amdgcn_ds_bpermute(bidx, __float_as_int(a[r].y)));
            b[r].x = __int_as_float(__builtin_amdgcn_ds_bpermute(bidx, __float_as_int(b[r].x)));
            b[r].y = __int_as_float(__builtin_amdgcn_ds_bpermute(bidx, __float_as_int(b[r].y)));
        }
        cnot_gate2<4, 3>(a, b, lane);
        cnot_gate2<3, 2>(a, b, lane);
        cnot_gate2<2, 1>(a, b, lane);
        cnot_gate2<1, 0>(a, b, lane);
        // cnot<0,9> fused into next layer's rot<9>
    }

    // ---- layers 1..3 (first gate consumes previous layer's trailing cnot<0,9>) ----
    for (int l = 1; l < NLAYERS; l++) {
        const float* gl = &gates[l * NQ * 8];
        {   float4 gA = *(const float4*)(gl);
            float4 gB = *(const float4*)(gl + 4);
            rot9_fused2(a, b, lane, gA, gB); }
#define ROTQ(Q) { float4 gA = *(const float4*)(gl + Q * 8); \
                  float4 gB = *(const float4*)(gl + Q * 8 + 4); \
                  rot_gate2<9 - Q>(a, b, lane, gA, gB); }
        ROTQ(1) ROTQ(2) ROTQ(3) ROTQ(4)
        ROTQ(5) ROTQ(6) ROTQ(7) ROTQ(8) ROTQ(9)
#undef ROTQ
#pragma unroll
        for (int r = 0; r < 16; r++) {
            a[r].x = __int_as_float(__builtin_amdgcn_ds_bpermute(bidx, __float_as_int(a[r].x)));
            a[r].y = __int_as_float(__builtin_amdgcn_ds_bpermute(bidx, __float_as_int(a[r].y)));
            b[r].x = __int_as_float(__builtin_amdgcn_ds_bpermute(bidx, __float_as_int(b[r].x)));
            b[r].y = __int_as_float(__builtin_amdgcn_ds_bpermute(bidx, __float_as_int(b[r].y)));
        }
        cnot_gate2<4, 3>(a, b, lane);
        cnot_gate2<3, 2>(a, b, lane);
        cnot_gate2<2, 1>(a, b, lane);
        cnot_gate2<1, 0>(a, b, lane);
    }
    // layer 3's trailing cnot<0,9> applied for real (measurement follows)
    cnot_gate2<0, 9>(a, b, lane);

    // ---- measurement: Z expectation per qubit, both states ----
    float S0 = 0.f, za3 = 0.f, za2 = 0.f, za1 = 0.f, za0 = 0.f;
    float S1 = 0.f, zb3 = 0.f, zb2 = 0.f, zb1 = 0.f, zb0 = 0.f;
#pragma unroll
    for (int r = 0; r < 16; r++) {
        float pa = a[r].x * a[r].x + a[r].y * a[r].y;
        float pb = b[r].x * b[r].x + b[r].y * b[r].y;
        S0 += pa;  S1 += pb;
        za3 += (r & 8) ? -pa : pa;   zb3 += (r & 8) ? -pb : pb;
        za2 += (r & 4) ? -pa : pa;   zb2 += (r & 4) ? -pb : pb;
        za1 += (r & 2) ? -pa : pa;   zb1 += (r & 2) ? -pb : pb;
        za0 += (r & 1) ? -pa : pa;   zb0 += (r & 1) ? -pb : pb;
    }
    float zqa[NQ], zqb[NQ];
    zqa[6] = za3; zqa[7] = za2; zqa[8] = za1; zqa[9] = za0;
    zqb[6] = zb3; zqb[7] = zb2; zqb[8] = zb1; zqb[9] = zb0;
#pragma unroll
    for (int q = 0; q < 6; q++) {                      // lane qubits: lane bit 5-q
        zqa[q] = ((lane >> (5 - q)) & 1) ? -S0 : S0;
        zqb[q] = ((lane >> (5 - q)) & 1) ? -S1 : S1;
    }
#pragma unroll
    for (int q = 0; q < NQ; q++) {
#pragma unroll
        for (int o = 1; o < 64; o <<= 1) {
            zqa[q] += __shfl_xor(zqa[q], o, 64);
            zqb[q] += __shfl_xor(zqb[q], o, 64);
        }
    }

    // ---- output projection: out = zq @ Wo^T + bo, both states ----
    if (lane < NQ) {
        const float* wrow = Wo + lane * NQ;
        float o0 = bo[lane], o1 = o0;
#pragma unroll
        for (int q = 0; q < NQ; q++) {
            float w = wrow[q];
            o0 += zqa[q] * w;
            o1 += zqb[q] * w;
        }
        out[(size_t)s0 * NQ + lane] = o0;
        out[(size_t)s1 * NQ + lane] = o1;
    }
}

extern "C" void kernel_launch(void* const* d_in, const int* in_sizes, int n_in,
                              void* d_out, int out_size, void* d_ws, size_t ws_size,
                              hipStream_t stream) {
    const float* x  = (const float*)d_in[0];
    const float* Wp = (const float*)d_in[1];
    const float* bp = (const float*)d_in[2];
    const float* qw = (const float*)d_in[3];
    const float* Wo = (const float*)d_in[4];
    const float* bo = (const float*)d_in[5];
    float* out = (float*)d_out;

    const int B = in_sizes[0] / D_IN;                    // 8192 states, two per wave/block
    const int blocks = (B + 1) / 2;
    hipLaunchKernelGGL(qnet_kernel, dim3(blocks), dim3(BLOCK), 0, stream,
                       x, Wp, bp, qw, Wo, bo, out, B);
}